// Round 8
// baseline (127.910 us; speedup 1.0000x reference)
//
#include <hip/hip_runtime.h>
#include <math.h>

#define DIN 128
#define DH 256
#define DOUT 40
#define MLP_ROWS 64

#define BSH 7                    // 128 nodes per bucket
#define BNODES 128
#define NBUK 391                 // ceil(50000/128)
#define CAP 4096                 // edge slots per bucket (mean ~2046, +8-pad ~2950)
#define PART_T 512
#define PART_EPB 4
#define PART_CHUNK (PART_T * PART_EPB)   // 2048 edges per block -> 391 blocks

typedef short short8 __attribute__((ext_vector_type(8)));
typedef float f32x4 __attribute__((ext_vector_type(4)));

// round-to-nearest-even float -> bf16 bits
__device__ inline unsigned f2bf(float f) {
    unsigned u = __float_as_uint(f);
    return (u + 0x7fffu + ((u >> 16) & 1u)) >> 16;
}
__device__ inline float bflo(unsigned u) { return __uint_as_float(u << 16); }
__device__ inline float bfhi(unsigned u) { return __uint_as_float(u & 0xffff0000u); }

// ---------- merged prep (xb/w1t/w2t) + bucket partition, gcur zeroed by memset ----
__global__ __launch_bounds__(PART_T) void k_prep_part(
    const float* __restrict__ x, const float* __restrict__ W1,
    const float* __restrict__ W2, const int* __restrict__ src,
    const int* __restrict__ dst, unsigned* __restrict__ xb,
    unsigned* __restrict__ w1t, unsigned* __restrict__ w2t,
    int* __restrict__ gcur, unsigned* __restrict__ raw, int E, int n64) {
    __shared__ int hist[NBUK];
    __shared__ int lbase[NBUK];
    int tid = threadIdx.x;

    // grid-stride prep: xb, w1t, w2t
    int prep_items = n64 + 256 * 64 + 48 * 128;
    int gsize = gridDim.x * PART_T;
    for (int i = blockIdx.x * PART_T + tid; i < prep_items; i += gsize) {
        if (i < n64) {
            float2 v = ((const float2*)x)[i];
            xb[i] = f2bf(v.x) | (f2bf(v.y) << 16);
        } else if (i < n64 + 256 * 64) {
            int j = i - n64;
            int c = j >> 6;
            int kk = (j & 63) * 2;
            w1t[j] = f2bf(W1[kk * DH + c]) | (f2bf(W1[(kk + 1) * DH + c]) << 16);
        } else {
            int j = i - n64 - 256 * 64;
            int col = j >> 7;
            int kk = (j & 127) * 2;
            float a = (col < DOUT) ? W2[kk * DOUT + col] : 0.f;
            float bb = (col < DOUT) ? W2[(kk + 1) * DOUT + col] : 0.f;
            w2t[j] = f2bf(a) | (f2bf(bb) << 16);
        }
    }

    // bucket partition of this block's edge chunk
    int base_e = blockIdx.x * PART_CHUNK;
    for (int i = tid; i < NBUK; i += PART_T) hist[i] = 0;
    __syncthreads();

    int s[PART_EPB], d[PART_EPB];
#pragma unroll
    for (int k = 0; k < PART_EPB; ++k) {
        int e = base_e + k * PART_T + tid;
        if (e < E) { s[k] = src[e]; d[k] = dst[e]; }
        else d[k] = -1;
    }
#pragma unroll
    for (int k = 0; k < PART_EPB; ++k)
        if (d[k] >= 0) atomicAdd(&hist[d[k] >> BSH], 1);
    __syncthreads();

    for (int b = tid; b < NBUK; b += PART_T) {
        int c = hist[b];
        lbase[b] = b * CAP + (c ? atomicAdd(&gcur[b], c) : 0);
    }
    __syncthreads();
    for (int i = tid; i < NBUK; i += PART_T) hist[i] = 0;  // reuse as local cursor
    __syncthreads();

#pragma unroll
    for (int k = 0; k < PART_EPB; ++k) {
        if (d[k] >= 0) {
            int b = d[k] >> BSH;
            int pos = lbase[b] + atomicAdd(&hist[b], 1);
            if (pos < (b + 1) * CAP)
                raw[pos] = ((unsigned)(d[k] & (BNODES - 1)) << 16) | (unsigned)s[k];
        }
    }
}

// one block per bucket: count -> 8-padded scan -> row_ptr/row_end/dinv -> reorder
__global__ __launch_bounds__(256) void k_bucket_csr(
    const unsigned* __restrict__ raw, const int* __restrict__ gcur,
    int* __restrict__ row_ptr, int* __restrict__ row_end,
    float* __restrict__ dinv, unsigned short* __restrict__ esrc, int n) {
    __shared__ int cnt[BNODES];
    __shared__ int scn[BNODES];
    __shared__ int lcur[BNODES];
    int b = blockIdx.x;
    int tid = threadIdx.x;
    int base = b * CAP;
    int size = gcur[b];
    if (size > CAP) size = CAP;

    if (tid < BNODES) cnt[tid] = 0;
    __syncthreads();
    for (int i = tid; i < size; i += 256)
        atomicAdd(&cnt[raw[base + i] >> 16], 1);
    __syncthreads();

    // inclusive scan of 8-padded counts (keeps every row start 8-aligned)
    if (tid < BNODES) scn[tid] = (cnt[tid] + 7) & ~7;
    __syncthreads();
    for (int off = 1; off < BNODES; off <<= 1) {
        int v = 0;
        if (tid < BNODES && tid >= off) v = scn[tid - off];
        __syncthreads();
        if (tid < BNODES) scn[tid] += v;
        __syncthreads();
    }
    if (tid < BNODES) {
        int c8 = (cnt[tid] + 7) & ~7;
        int excl = scn[tid] - c8;
        if (excl > CAP) excl = CAP;
        int re = excl + cnt[tid];
        if (re > CAP) re = CAP;
        lcur[tid] = excl;
        int g = b * BNODES + tid;
        if (g < n) {
            row_ptr[g] = base + excl;
            row_end[g] = base + re;
            dinv[g]    = rsqrtf((float)cnt[tid] + 1.0f);
        }
    }
    __syncthreads();
    for (int i = tid; i < size; i += 256) {
        unsigned rec = raw[base + i];
        int pos = atomicAdd(&lcur[rec >> 16], 1);
        if (pos < CAP) esrc[base + pos] = (unsigned short)(rec & 0xffffu);
    }
}

// -------- layer 1 gather: 2 nodes/wave, uint4 esrc batches, unroll-16 ----------
__global__ void k_gather_agg1(const uint2* __restrict__ xb2,
                              const unsigned short* __restrict__ esrc,
                              const int* __restrict__ row_ptr, const int* __restrict__ row_end,
                              const float* __restrict__ dinv, uint2* __restrict__ axb2, int n) {
    int wid = (blockIdx.x * blockDim.x + threadIdx.x) >> 6;
    int lane = threadIdx.x & 63;
    int node = wid * 2 + (lane >> 5);
    int hl = lane & 31;
    if (node >= n) return;
    int beg = row_ptr[node], end = row_end[node];
    float dn = dinv[node];
    uint2 sv = xb2[(size_t)node * 32 + hl];
    float ax = dn * bflo(sv.x), ay = dn * bfhi(sv.x);
    float az = dn * bflo(sv.y), aw = dn * bfhi(sv.y);
    int t = beg;
    for (; t + 16 <= end; t += 16) {
        uint4 q0 = *(const uint4*)(esrc + t);
        uint4 q1 = *(const uint4*)(esrc + t + 8);
        int s0 = q0.x & 0xffff, s1 = q0.x >> 16, s2 = q0.y & 0xffff, s3 = q0.y >> 16;
        int s4 = q0.z & 0xffff, s5 = q0.z >> 16, s6 = q0.w & 0xffff, s7 = q0.w >> 16;
        int s8 = q1.x & 0xffff, s9 = q1.x >> 16, sa = q1.y & 0xffff, sb = q1.y >> 16;
        int sc = q1.z & 0xffff, sd = q1.z >> 16, se = q1.w & 0xffff, sf = q1.w >> 16;
        float w0 = dinv[s0], w1 = dinv[s1], w2 = dinv[s2], w3 = dinv[s3];
        float w4 = dinv[s4], w5 = dinv[s5], w6 = dinv[s6], w7 = dinv[s7];
        float w8 = dinv[s8], w9 = dinv[s9], wa = dinv[sa], wb = dinv[sb];
        float wc = dinv[sc], wd = dinv[sd], we = dinv[se], wf = dinv[sf];
        uint2 v0 = xb2[(size_t)s0 * 32 + hl], v1 = xb2[(size_t)s1 * 32 + hl];
        uint2 v2 = xb2[(size_t)s2 * 32 + hl], v3 = xb2[(size_t)s3 * 32 + hl];
        uint2 v4 = xb2[(size_t)s4 * 32 + hl], v5 = xb2[(size_t)s5 * 32 + hl];
        uint2 v6 = xb2[(size_t)s6 * 32 + hl], v7 = xb2[(size_t)s7 * 32 + hl];
        uint2 v8 = xb2[(size_t)s8 * 32 + hl], v9 = xb2[(size_t)s9 * 32 + hl];
        uint2 va = xb2[(size_t)sa * 32 + hl], vb = xb2[(size_t)sb * 32 + hl];
        uint2 vc = xb2[(size_t)sc * 32 + hl], vd = xb2[(size_t)sd * 32 + hl];
        uint2 ve = xb2[(size_t)se * 32 + hl], vf = xb2[(size_t)sf * 32 + hl];
        ax += w0 * bflo(v0.x) + w1 * bflo(v1.x) + w2 * bflo(v2.x) + w3 * bflo(v3.x)
            + w4 * bflo(v4.x) + w5 * bflo(v5.x) + w6 * bflo(v6.x) + w7 * bflo(v7.x)
            + w8 * bflo(v8.x) + w9 * bflo(v9.x) + wa * bflo(va.x) + wb * bflo(vb.x)
            + wc * bflo(vc.x) + wd * bflo(vd.x) + we * bflo(ve.x) + wf * bflo(vf.x);
        ay += w0 * bfhi(v0.x) + w1 * bfhi(v1.x) + w2 * bfhi(v2.x) + w3 * bfhi(v3.x)
            + w4 * bfhi(v4.x) + w5 * bfhi(v5.x) + w6 * bfhi(v6.x) + w7 * bfhi(v7.x)
            + w8 * bfhi(v8.x) + w9 * bfhi(v9.x) + wa * bfhi(va.x) + wb * bfhi(vb.x)
            + wc * bfhi(vc.x) + wd * bfhi(vd.x) + we * bfhi(ve.x) + wf * bfhi(vf.x);
        az += w0 * bflo(v0.y) + w1 * bflo(v1.y) + w2 * bflo(v2.y) + w3 * bflo(v3.y)
            + w4 * bflo(v4.y) + w5 * bflo(v5.y) + w6 * bflo(v6.y) + w7 * bflo(v7.y)
            + w8 * bflo(v8.y) + w9 * bflo(v9.y) + wa * bflo(va.y) + wb * bflo(vb.y)
            + wc * bflo(vc.y) + wd * bflo(vd.y) + we * bflo(ve.y) + wf * bflo(vf.y);
        aw += w0 * bfhi(v0.y) + w1 * bfhi(v1.y) + w2 * bfhi(v2.y) + w3 * bfhi(v3.y)
            + w4 * bfhi(v4.y) + w5 * bfhi(v5.y) + w6 * bfhi(v6.y) + w7 * bfhi(v7.y)
            + w8 * bfhi(v8.y) + w9 * bfhi(v9.y) + wa * bfhi(va.y) + wb * bfhi(vb.y)
            + wc * bfhi(vc.y) + wd * bfhi(vd.y) + we * bfhi(ve.y) + wf * bfhi(vf.y);
    }
    for (; t + 8 <= end; t += 8) {
        uint4 q0 = *(const uint4*)(esrc + t);
        int s0 = q0.x & 0xffff, s1 = q0.x >> 16, s2 = q0.y & 0xffff, s3 = q0.y >> 16;
        int s4 = q0.z & 0xffff, s5 = q0.z >> 16, s6 = q0.w & 0xffff, s7 = q0.w >> 16;
        float w0 = dinv[s0], w1 = dinv[s1], w2 = dinv[s2], w3 = dinv[s3];
        float w4 = dinv[s4], w5 = dinv[s5], w6 = dinv[s6], w7 = dinv[s7];
        uint2 v0 = xb2[(size_t)s0 * 32 + hl], v1 = xb2[(size_t)s1 * 32 + hl];
        uint2 v2 = xb2[(size_t)s2 * 32 + hl], v3 = xb2[(size_t)s3 * 32 + hl];
        uint2 v4 = xb2[(size_t)s4 * 32 + hl], v5 = xb2[(size_t)s5 * 32 + hl];
        uint2 v6 = xb2[(size_t)s6 * 32 + hl], v7 = xb2[(size_t)s7 * 32 + hl];
        ax += w0 * bflo(v0.x) + w1 * bflo(v1.x) + w2 * bflo(v2.x) + w3 * bflo(v3.x)
            + w4 * bflo(v4.x) + w5 * bflo(v5.x) + w6 * bflo(v6.x) + w7 * bflo(v7.x);
        ay += w0 * bfhi(v0.x) + w1 * bfhi(v1.x) + w2 * bfhi(v2.x) + w3 * bfhi(v3.x)
            + w4 * bfhi(v4.x) + w5 * bfhi(v5.x) + w6 * bfhi(v6.x) + w7 * bfhi(v7.x);
        az += w0 * bflo(v0.y) + w1 * bflo(v1.y) + w2 * bflo(v2.y) + w3 * bflo(v3.y)
            + w4 * bflo(v4.y) + w5 * bflo(v5.y) + w6 * bflo(v6.y) + w7 * bflo(v7.y);
        aw += w0 * bfhi(v0.y) + w1 * bfhi(v1.y) + w2 * bfhi(v2.y) + w3 * bfhi(v3.y)
            + w4 * bfhi(v4.y) + w5 * bfhi(v5.y) + w6 * bfhi(v6.y) + w7 * bfhi(v7.y);
    }
    for (; t < end; ++t) {
        int s = esrc[t];
        float w = dinv[s];
        uint2 v = xb2[(size_t)s * 32 + hl];
        ax += w * bflo(v.x); ay += w * bfhi(v.x);
        az += w * bflo(v.y); aw += w * bfhi(v.y);
    }
    ax *= dn; ay *= dn; az *= dn; aw *= dn;
    axb2[(size_t)node * 32 + hl] =
        make_uint2(f2bf(ax) | (f2bf(ay) << 16), f2bf(az) | (f2bf(aw) << 16));
}

// -------------------- fused MFMA MLP: pb = bf16(relu(ax@W1+b1)@W2) -------------
__global__ __launch_bounds__(256) void k_mlp_mfma(
    const unsigned short* __restrict__ axb, const unsigned short* __restrict__ w1t,
    const float* __restrict__ b1, const unsigned short* __restrict__ w2t,
    unsigned short* __restrict__ pb, int n) {
    __shared__ __align__(16) char smem[65536];
    const int tid = threadIdx.x;
    const int lane = tid & 63;
    const int wv = tid >> 6;
    const int l15 = lane & 15;
    const int lg = lane >> 4;
    const int blockRow = blockIdx.x * MLP_ROWS;

    for (int i = tid; i < 256 * 16; i += 256) {
        int j = i >> 4, seg = i & 15;
        short8 v = *(const short8*)(w1t + j * 128 + seg * 8);
        *(short8*)(smem + j * 256 + ((seg * 16) ^ ((j & 7) << 4))) = v;
    }

    int arow = blockRow + wv * 16 + l15;
    if (arow >= n) arow = n - 1;
    const unsigned short* axp = axb + (size_t)arow * DIN + lg * 8;
    short8 aF[4];
#pragma unroll
    for (int ks = 0; ks < 4; ++ks) aF[ks] = *(const short8*)(axp + ks * 32);

    __syncthreads();

    f32x4 acc[16];
#pragma unroll
    for (int nt = 0; nt < 16; ++nt) acc[nt] = (f32x4){0.f, 0.f, 0.f, 0.f};
#pragma unroll
    for (int ks = 0; ks < 4; ++ks) {
        int kb = (ks * 32 + lg * 8) * 2;
#pragma unroll
        for (int nt = 0; nt < 16; ++nt) {
            int j = nt * 16 + l15;
            short8 bF = *(const short8*)(smem + j * 256 + (kb ^ ((j & 7) << 4)));
            acc[nt] = __builtin_amdgcn_mfma_f32_16x16x32_bf16(aF[ks], bF, acc[nt], 0, 0, 0);
        }
    }
    __syncthreads();

    unsigned short* s_h = (unsigned short*)smem;             // [64][264] bf16
    unsigned short* s_w2 = (unsigned short*)(smem + 33792);  // [48][264] bf16

#pragma unroll
    for (int nt = 0; nt < 16; ++nt) {
        int col = nt * 16 + l15;
        float bias = b1[col];
#pragma unroll
        for (int r = 0; r < 4; ++r) {
            int row = wv * 16 + lg * 4 + r;
            float v = fmaxf(acc[nt][r] + bias, 0.f);
            s_h[row * 264 + col] = (unsigned short)f2bf(v);
        }
    }
    for (int i = tid; i < 48 * 32; i += 256) {
        int j = i >> 5, seg = i & 31;
        short8 v = *(const short8*)(w2t + j * 256 + seg * 8);
        *(short8*)(s_w2 + j * 264 + seg * 8) = v;
    }
    __syncthreads();

    f32x4 acc2[3];
#pragma unroll
    for (int t = 0; t < 3; ++t) acc2[t] = (f32x4){0.f, 0.f, 0.f, 0.f};
#pragma unroll
    for (int ks = 0; ks < 8; ++ks) {
        int k = ks * 32 + lg * 8;
        short8 aH = *(const short8*)(s_h + (wv * 16 + l15) * 264 + k);
#pragma unroll
        for (int t = 0; t < 3; ++t) {
            short8 bF = *(const short8*)(s_w2 + (t * 16 + l15) * 264 + k);
            acc2[t] = __builtin_amdgcn_mfma_f32_16x16x32_bf16(aH, bF, acc2[t], 0, 0, 0);
        }
    }
#pragma unroll
    for (int t = 0; t < 3; ++t) {
        int col = t * 16 + l15;
        if (col < DOUT) {
#pragma unroll
            for (int r = 0; r < 4; ++r) {
                int row = blockRow + wv * 16 + lg * 4 + r;
                if (row < n) pb[(size_t)row * DOUT + col] = (unsigned short)f2bf(acc2[t][r]);
            }
        }
    }
}

// ------ layer 2 gather (bf16 p): 2 nodes/wave, uint4 esrc batches, unroll-16 -----
__global__ void k_gather2_lsm(const unsigned* __restrict__ pbu,
                              const unsigned short* __restrict__ esrc,
                              const int* __restrict__ row_ptr, const int* __restrict__ row_end,
                              const float* __restrict__ dinv, const float* __restrict__ b2,
                              float* __restrict__ out, int n) {
    int wid = (blockIdx.x * blockDim.x + threadIdx.x) >> 6;
    int lane = threadIdx.x & 63;
    int node = wid * 2 + (lane >> 5);
    int hl = lane & 31;
    if (node >= n) return;
    int beg = row_ptr[node], end = row_end[node];
    float dn = dinv[node];
    int cl = (hl < 20) ? hl : 0;   // clamped uint column (2 bf16 cols per uint)
    unsigned pv = pbu[(size_t)node * 20 + cl];
    float accx = dn * bflo(pv);
    float accy = dn * bfhi(pv);
    int t = beg;
    for (; t + 16 <= end; t += 16) {
        uint4 q0 = *(const uint4*)(esrc + t);
        uint4 q1 = *(const uint4*)(esrc + t + 8);
        int s0 = q0.x & 0xffff, s1 = q0.x >> 16, s2 = q0.y & 0xffff, s3 = q0.y >> 16;
        int s4 = q0.z & 0xffff, s5 = q0.z >> 16, s6 = q0.w & 0xffff, s7 = q0.w >> 16;
        int s8 = q1.x & 0xffff, s9 = q1.x >> 16, sa = q1.y & 0xffff, sb = q1.y >> 16;
        int sc = q1.z & 0xffff, sd = q1.z >> 16, se = q1.w & 0xffff, sf = q1.w >> 16;
        float w0 = dinv[s0], w1 = dinv[s1], w2 = dinv[s2], w3 = dinv[s3];
        float w4 = dinv[s4], w5 = dinv[s5], w6 = dinv[s6], w7 = dinv[s7];
        float w8 = dinv[s8], w9 = dinv[s9], wa = dinv[sa], wb = dinv[sb];
        float wc = dinv[sc], wd = dinv[sd], we = dinv[se], wf = dinv[sf];
        unsigned p0 = pbu[(size_t)s0 * 20 + cl], p1 = pbu[(size_t)s1 * 20 + cl];
        unsigned p2 = pbu[(size_t)s2 * 20 + cl], p3 = pbu[(size_t)s3 * 20 + cl];
        unsigned p4 = pbu[(size_t)s4 * 20 + cl], p5 = pbu[(size_t)s5 * 20 + cl];
        unsigned p6 = pbu[(size_t)s6 * 20 + cl], p7 = pbu[(size_t)s7 * 20 + cl];
        unsigned p8 = pbu[(size_t)s8 * 20 + cl], p9 = pbu[(size_t)s9 * 20 + cl];
        unsigned pa = pbu[(size_t)sa * 20 + cl], pb_ = pbu[(size_t)sb * 20 + cl];
        unsigned pc = pbu[(size_t)sc * 20 + cl], pd = pbu[(size_t)sd * 20 + cl];
        unsigned pe = pbu[(size_t)se * 20 + cl], pf = pbu[(size_t)sf * 20 + cl];
        accx += w0 * bflo(p0) + w1 * bflo(p1) + w2 * bflo(p2) + w3 * bflo(p3)
              + w4 * bflo(p4) + w5 * bflo(p5) + w6 * bflo(p6) + w7 * bflo(p7)
              + w8 * bflo(p8) + w9 * bflo(p9) + wa * bflo(pa) + wb * bflo(pb_)
              + wc * bflo(pc) + wd * bflo(pd) + we * bflo(pe) + wf * bflo(pf);
        accy += w0 * bfhi(p0) + w1 * bfhi(p1) + w2 * bfhi(p2) + w3 * bfhi(p3)
              + w4 * bfhi(p4) + w5 * bfhi(p5) + w6 * bfhi(p6) + w7 * bfhi(p7)
              + w8 * bfhi(p8) + w9 * bfhi(p9) + wa * bfhi(pa) + wb * bfhi(pb_)
              + wc * bfhi(pc) + wd * bfhi(pd) + we * bfhi(pe) + wf * bfhi(pf);
    }
    for (; t + 8 <= end; t += 8) {
        uint4 q0 = *(const uint4*)(esrc + t);
        int s0 = q0.x & 0xffff, s1 = q0.x >> 16, s2 = q0.y & 0xffff, s3 = q0.y >> 16;
        int s4 = q0.z & 0xffff, s5 = q0.z >> 16, s6 = q0.w & 0xffff, s7 = q0.w >> 16;
        float w0 = dinv[s0], w1 = dinv[s1], w2 = dinv[s2], w3 = dinv[s3];
        float w4 = dinv[s4], w5 = dinv[s5], w6 = dinv[s6], w7 = dinv[s7];
        unsigned p0 = pbu[(size_t)s0 * 20 + cl], p1 = pbu[(size_t)s1 * 20 + cl];
        unsigned p2 = pbu[(size_t)s2 * 20 + cl], p3 = pbu[(size_t)s3 * 20 + cl];
        unsigned p4 = pbu[(size_t)s4 * 20 + cl], p5 = pbu[(size_t)s5 * 20 + cl];
        unsigned p6 = pbu[(size_t)s6 * 20 + cl], p7 = pbu[(size_t)s7 * 20 + cl];
        accx += w0 * bflo(p0) + w1 * bflo(p1) + w2 * bflo(p2) + w3 * bflo(p3)
              + w4 * bflo(p4) + w5 * bflo(p5) + w6 * bflo(p6) + w7 * bflo(p7);
        accy += w0 * bfhi(p0) + w1 * bfhi(p1) + w2 * bfhi(p2) + w3 * bfhi(p3)
              + w4 * bfhi(p4) + w5 * bfhi(p5) + w6 * bfhi(p6) + w7 * bfhi(p7);
    }
    for (; t < end; ++t) {
        int s = esrc[t];
        float w = dinv[s];
        unsigned p = pbu[(size_t)s * 20 + cl];
        accx += w * bflo(p);
        accy += w * bfhi(p);
    }
    float vx = -INFINITY, vy = -INFINITY;
    if (hl < 20) {
        float2 bv = ((const float2*)b2)[hl];
        vx = dn * accx + bv.x;
        vy = dn * accy + bv.y;
    }
    float m = fmaxf(vx, vy);
#pragma unroll
    for (int off = 16; off; off >>= 1) m = fmaxf(m, __shfl_xor(m, off, 32));
    float ex = (hl < 20) ? (expf(vx - m) + expf(vy - m)) : 0.f;
    float ssum = ex;
#pragma unroll
    for (int off = 16; off; off >>= 1) ssum += __shfl_xor(ssum, off, 32);
    float ls = logf(ssum);
    if (hl < 20)
        ((float2*)(out + (size_t)node * DOUT))[hl] = make_float2(vx - m - ls, vy - m - ls);
}

extern "C" void kernel_launch(void* const* d_in, const int* in_sizes, int n_in,
                              void* d_out, int out_size, void* d_ws, size_t ws_size,
                              hipStream_t stream) {
    const float* x  = (const float*)d_in[0];
    const int*   ei = (const int*)d_in[1];
    const float* W1 = (const float*)d_in[2];
    const float* b1 = (const float*)d_in[3];
    const float* W2 = (const float*)d_in[4];
    const float* b2 = (const float*)d_in[5];
    float* out = (float*)d_out;

    int n = in_sizes[0] / DIN;   // 50000
    int E = in_sizes[1] / 2;     // 800000
    const int* src = ei;
    const int* dst = ei + E;

    // workspace layout (~36 MB)
    int*            gcur    = (int*)d_ws;                          // 512 (NBUK used)
    int*            row_ptr = gcur + 512;                          // n
    int*            row_end = row_ptr + n;                         // n
    float*          dinv    = (float*)(row_end + n);               // n
    unsigned*       w1t     = (unsigned*)(dinv + n);               // 16384
    unsigned*       w2t     = w1t + 16384;                         // 6144
    unsigned*       raw     = w2t + 6144;                          // NBUK*CAP uint
    unsigned short* esrc    = (unsigned short*)(raw + (size_t)NBUK * CAP); // NBUK*CAP us
    unsigned*       xb      = (unsigned*)(esrc + (size_t)NBUK * CAP);      // n*64
    unsigned*       axb     = xb + (size_t)n * 64;                 // n*64
    unsigned short* pb      = (unsigned short*)xb;                 // n*40 bf16, overlays dead xb

    const int B = 256;
    int part_blocks = (E + PART_CHUNK - 1) / PART_CHUNK;           // 391
    int npairs = (n + 1) / 2;                                      // 2 nodes per wave
    int gath_blocks = (int)(((size_t)npairs * 64 + B - 1) / B);

    hipMemsetAsync(gcur, 0, NBUK * sizeof(int), stream);
    k_prep_part<<<part_blocks, PART_T, 0, stream>>>(
        x, W1, W2, src, dst, xb, w1t, w2t, gcur, raw, E, n * 64);
    k_bucket_csr<<<NBUK, B, 0, stream>>>(raw, gcur, row_ptr, row_end, dinv, esrc, n);
    k_gather_agg1<<<gath_blocks, B, 0, stream>>>(
        (const uint2*)xb, esrc, row_ptr, row_end, dinv, (uint2*)axb, n);
    k_mlp_mfma<<<(n + MLP_ROWS - 1) / MLP_ROWS, B, 0, stream>>>(
        (const unsigned short*)axb, (const unsigned short*)w1t, b1,
        (const unsigned short*)w2t, pb, n);
    k_gather2_lsm<<<gath_blocks, B, 0, stream>>>(
        (const unsigned*)pb, esrc, row_ptr, row_end, dinv, b2, out, n);
}

// Round 9
// 118.271 us; speedup vs baseline: 1.0815x; 1.0815x over previous
//
#include <hip/hip_runtime.h>
#include <math.h>

#define DIN 128
#define DH 256
#define DOUT 40
#define MLP_ROWS 64

#define BSH 7                    // 128 nodes per bucket
#define BNODES 128
#define NBUK 391                 // ceil(50000/128)
#define CAP 4096                 // edge slots per bucket (mean ~2046, +8-pad worst ~3.2K)
#define PART_T 512
#define PART_EPB 8
#define PART_CHUNK (PART_T * PART_EPB)   // 4096 edges per block -> 196 blocks

typedef short short8 __attribute__((ext_vector_type(8)));
typedef float f32x4 __attribute__((ext_vector_type(4)));

// round-to-nearest-even float -> bf16 bits
__device__ inline unsigned f2bf(float f) {
    unsigned u = __float_as_uint(f);
    return (u + 0x7fffu + ((u >> 16) & 1u)) >> 16;
}
__device__ inline float bflo(unsigned u) { return __uint_as_float(u << 16); }
__device__ inline float bfhi(unsigned u) { return __uint_as_float(u & 0xffff0000u); }

// -------------------- bucket-partition CSR build --------------------

// 196 blocks x 512 threads, 4096 edges/block: LDS histogram -> one global
// atomicAdd per (block,bucket) -> write packed {dstLow7<<16 | src16} records
__global__ __launch_bounds__(PART_T) void k_partition(
    const int* __restrict__ src, const int* __restrict__ dst,
    int* __restrict__ gcur, unsigned* __restrict__ raw, int E) {
    __shared__ int hist[NBUK];
    __shared__ int lbase[NBUK];
    int tid = threadIdx.x;
    int base_e = blockIdx.x * PART_CHUNK;

    for (int i = tid; i < NBUK; i += PART_T) hist[i] = 0;
    __syncthreads();

    int s[PART_EPB], d[PART_EPB];
#pragma unroll
    for (int k = 0; k < PART_EPB; ++k) {
        int e = base_e + k * PART_T + tid;
        if (e < E) { s[k] = src[e]; d[k] = dst[e]; }
        else d[k] = -1;
    }
#pragma unroll
    for (int k = 0; k < PART_EPB; ++k)
        if (d[k] >= 0) atomicAdd(&hist[d[k] >> BSH], 1);
    __syncthreads();

    for (int b = tid; b < NBUK; b += PART_T) {
        int c = hist[b];
        lbase[b] = c ? atomicAdd(&gcur[b], c) : 0;   // gcur pre-inited to b*CAP
    }
    __syncthreads();
    for (int i = tid; i < NBUK; i += PART_T) hist[i] = 0;  // reuse as local cursor
    __syncthreads();

#pragma unroll
    for (int k = 0; k < PART_EPB; ++k) {
        if (d[k] >= 0) {
            int b = d[k] >> BSH;
            int pos = lbase[b] + atomicAdd(&hist[b], 1);
            if (pos < (b + 1) * CAP)
                raw[pos] = ((unsigned)(d[k] & (BNODES - 1)) << 16) | (unsigned)s[k];
        }
    }
}

// one block per bucket: count -> 8-padded scan (8-aligned row starts) ->
// row_ptr/row_end/dinv -> reorder into dst-grouped esrc (ushort)
__global__ __launch_bounds__(256) void k_bucket_csr(
    const unsigned* __restrict__ raw, const int* __restrict__ gcur,
    int* __restrict__ row_ptr, int* __restrict__ row_end,
    float* __restrict__ dinv, unsigned short* __restrict__ esrc, int n) {
    __shared__ int cnt[BNODES];
    __shared__ int scn[BNODES];
    __shared__ int lcur[BNODES];
    int b = blockIdx.x;
    int tid = threadIdx.x;
    int base = b * CAP;
    int size = gcur[b] - base;
    if (size > CAP) size = CAP;

    if (tid < BNODES) cnt[tid] = 0;
    __syncthreads();
    for (int i = tid; i < size; i += 256)
        atomicAdd(&cnt[raw[base + i] >> 16], 1);
    __syncthreads();

    // inclusive scan of 8-padded counts (keeps every row start 8-aligned)
    if (tid < BNODES) scn[tid] = (cnt[tid] + 7) & ~7;
    __syncthreads();
    for (int off = 1; off < BNODES; off <<= 1) {
        int v = 0;
        if (tid < BNODES && tid >= off) v = scn[tid - off];
        __syncthreads();
        if (tid < BNODES) scn[tid] += v;
        __syncthreads();
    }
    if (tid < BNODES) {
        int c8 = (cnt[tid] + 7) & ~7;
        int excl = scn[tid] - c8;
        if (excl > CAP) excl = CAP;
        int re = excl + cnt[tid];
        if (re > CAP) re = CAP;
        lcur[tid] = excl;
        int g = b * BNODES + tid;
        if (g < n) {
            row_ptr[g] = base + excl;
            row_end[g] = base + re;
            dinv[g]    = rsqrtf((float)cnt[tid] + 1.0f);
        }
    }
    __syncthreads();
    for (int i = tid; i < size; i += 256) {
        unsigned rec = raw[base + i];
        int pos = atomicAdd(&lcur[rec >> 16], 1);
        if (pos < CAP) esrc[base + pos] = (unsigned short)(rec & 0xffffu);
    }
}

// -------------------- merged prep: xb, w1t, w2t, gcur-init --------------------
__global__ void k_prep(const float* __restrict__ x, const float* __restrict__ W1,
                       const float* __restrict__ W2, unsigned* __restrict__ xb,
                       unsigned* __restrict__ w1t, unsigned* __restrict__ w2t,
                       int* __restrict__ gcur, int n64) {
    int i = blockIdx.x * blockDim.x + threadIdx.x;
    if (i < n64) {
        float2 v = ((const float2*)x)[i];
        xb[i] = f2bf(v.x) | (f2bf(v.y) << 16);
        return;
    }
    i -= n64;
    if (i < 256 * 64) {
        int c = i >> 6;
        int kk = (i & 63) * 2;
        w1t[i] = f2bf(W1[kk * DH + c]) | (f2bf(W1[(kk + 1) * DH + c]) << 16);
        return;
    }
    i -= 256 * 64;
    if (i < 48 * 128) {
        int col = i >> 7;
        int kk = (i & 127) * 2;
        float a = (col < DOUT) ? W2[kk * DOUT + col] : 0.f;
        float bb = (col < DOUT) ? W2[(kk + 1) * DOUT + col] : 0.f;
        w2t[i] = f2bf(a) | (f2bf(bb) << 16);
        return;
    }
    i -= 48 * 128;
    if (i < NBUK) gcur[i] = i * CAP;
}

// ------ layer 1 gather: 2 nodes/wave, uint4 esrc batch (8 edges), unroll-8 ------
__global__ void k_gather_agg1(const uint2* __restrict__ xb2,
                              const unsigned short* __restrict__ esrc,
                              const int* __restrict__ row_ptr, const int* __restrict__ row_end,
                              const float* __restrict__ dinv, uint2* __restrict__ axb2, int n) {
    int wid = (blockIdx.x * blockDim.x + threadIdx.x) >> 6;
    int lane = threadIdx.x & 63;
    int node = wid * 2 + (lane >> 5);
    int hl = lane & 31;
    if (node >= n) return;
    int beg = row_ptr[node], end = row_end[node];
    float dn = dinv[node];
    uint2 sv = xb2[(size_t)node * 32 + hl];
    float ax = dn * bflo(sv.x), ay = dn * bfhi(sv.x);
    float az = dn * bflo(sv.y), aw = dn * bfhi(sv.y);
    int t = beg;
    for (; t + 8 <= end; t += 8) {
        uint4 q = *(const uint4*)(esrc + t);      // 8 edges in one 16B load (8-aligned)
        int s0 = q.x & 0xffff, s1 = q.x >> 16, s2 = q.y & 0xffff, s3 = q.y >> 16;
        int s4 = q.z & 0xffff, s5 = q.z >> 16, s6 = q.w & 0xffff, s7 = q.w >> 16;
        float w0 = dinv[s0], w1 = dinv[s1], w2 = dinv[s2], w3 = dinv[s3];
        float w4 = dinv[s4], w5 = dinv[s5], w6 = dinv[s6], w7 = dinv[s7];
        uint2 v0 = xb2[(size_t)s0 * 32 + hl], v1 = xb2[(size_t)s1 * 32 + hl];
        uint2 v2 = xb2[(size_t)s2 * 32 + hl], v3 = xb2[(size_t)s3 * 32 + hl];
        uint2 v4 = xb2[(size_t)s4 * 32 + hl], v5 = xb2[(size_t)s5 * 32 + hl];
        uint2 v6 = xb2[(size_t)s6 * 32 + hl], v7 = xb2[(size_t)s7 * 32 + hl];
        ax += w0 * bflo(v0.x) + w1 * bflo(v1.x) + w2 * bflo(v2.x) + w3 * bflo(v3.x)
            + w4 * bflo(v4.x) + w5 * bflo(v5.x) + w6 * bflo(v6.x) + w7 * bflo(v7.x);
        ay += w0 * bfhi(v0.x) + w1 * bfhi(v1.x) + w2 * bfhi(v2.x) + w3 * bfhi(v3.x)
            + w4 * bfhi(v4.x) + w5 * bfhi(v5.x) + w6 * bfhi(v6.x) + w7 * bfhi(v7.x);
        az += w0 * bflo(v0.y) + w1 * bflo(v1.y) + w2 * bflo(v2.y) + w3 * bflo(v3.y)
            + w4 * bflo(v4.y) + w5 * bflo(v5.y) + w6 * bflo(v6.y) + w7 * bflo(v7.y);
        aw += w0 * bfhi(v0.y) + w1 * bfhi(v1.y) + w2 * bfhi(v2.y) + w3 * bfhi(v3.y)
            + w4 * bfhi(v4.y) + w5 * bfhi(v5.y) + w6 * bfhi(v6.y) + w7 * bfhi(v7.y);
    }
    for (; t < end; ++t) {
        int s = esrc[t];
        float w = dinv[s];
        uint2 v = xb2[(size_t)s * 32 + hl];
        ax += w * bflo(v.x); ay += w * bfhi(v.x);
        az += w * bflo(v.y); aw += w * bfhi(v.y);
    }
    ax *= dn; ay *= dn; az *= dn; aw *= dn;
    axb2[(size_t)node * 32 + hl] =
        make_uint2(f2bf(ax) | (f2bf(ay) << 16), f2bf(az) | (f2bf(aw) << 16));
}

// -------------------- fused MFMA MLP: pb = bf16(relu(ax@W1+b1)@W2) -------------
__global__ __launch_bounds__(256) void k_mlp_mfma(
    const unsigned short* __restrict__ axb, const unsigned short* __restrict__ w1t,
    const float* __restrict__ b1, const unsigned short* __restrict__ w2t,
    unsigned short* __restrict__ pb, int n) {
    __shared__ __align__(16) char smem[65536];
    const int tid = threadIdx.x;
    const int lane = tid & 63;
    const int wv = tid >> 6;
    const int l15 = lane & 15;
    const int lg = lane >> 4;
    const int blockRow = blockIdx.x * MLP_ROWS;

    for (int i = tid; i < 256 * 16; i += 256) {
        int j = i >> 4, seg = i & 15;
        short8 v = *(const short8*)(w1t + j * 128 + seg * 8);
        *(short8*)(smem + j * 256 + ((seg * 16) ^ ((j & 7) << 4))) = v;
    }

    int arow = blockRow + wv * 16 + l15;
    if (arow >= n) arow = n - 1;
    const unsigned short* axp = axb + (size_t)arow * DIN + lg * 8;
    short8 aF[4];
#pragma unroll
    for (int ks = 0; ks < 4; ++ks) aF[ks] = *(const short8*)(axp + ks * 32);

    __syncthreads();

    f32x4 acc[16];
#pragma unroll
    for (int nt = 0; nt < 16; ++nt) acc[nt] = (f32x4){0.f, 0.f, 0.f, 0.f};
#pragma unroll
    for (int ks = 0; ks < 4; ++ks) {
        int kb = (ks * 32 + lg * 8) * 2;
#pragma unroll
        for (int nt = 0; nt < 16; ++nt) {
            int j = nt * 16 + l15;
            short8 bF = *(const short8*)(smem + j * 256 + (kb ^ ((j & 7) << 4)));
            acc[nt] = __builtin_amdgcn_mfma_f32_16x16x32_bf16(aF[ks], bF, acc[nt], 0, 0, 0);
        }
    }
    __syncthreads();

    unsigned short* s_h = (unsigned short*)smem;             // [64][264] bf16
    unsigned short* s_w2 = (unsigned short*)(smem + 33792);  // [48][264] bf16

#pragma unroll
    for (int nt = 0; nt < 16; ++nt) {
        int col = nt * 16 + l15;
        float bias = b1[col];
#pragma unroll
        for (int r = 0; r < 4; ++r) {
            int row = wv * 16 + lg * 4 + r;
            float v = fmaxf(acc[nt][r] + bias, 0.f);
            s_h[row * 264 + col] = (unsigned short)f2bf(v);
        }
    }
    for (int i = tid; i < 48 * 32; i += 256) {
        int j = i >> 5, seg = i & 31;
        short8 v = *(const short8*)(w2t + j * 256 + seg * 8);
        *(short8*)(s_w2 + j * 264 + seg * 8) = v;
    }
    __syncthreads();

    f32x4 acc2[3];
#pragma unroll
    for (int t = 0; t < 3; ++t) acc2[t] = (f32x4){0.f, 0.f, 0.f, 0.f};
#pragma unroll
    for (int ks = 0; ks < 8; ++ks) {
        int k = ks * 32 + lg * 8;
        short8 aH = *(const short8*)(s_h + (wv * 16 + l15) * 264 + k);
#pragma unroll
        for (int t = 0; t < 3; ++t) {
            short8 bF = *(const short8*)(s_w2 + (t * 16 + l15) * 264 + k);
            acc2[t] = __builtin_amdgcn_mfma_f32_16x16x32_bf16(aH, bF, acc2[t], 0, 0, 0);
        }
    }
#pragma unroll
    for (int t = 0; t < 3; ++t) {
        int col = t * 16 + l15;
        if (col < DOUT) {
#pragma unroll
            for (int r = 0; r < 4; ++r) {
                int row = blockRow + wv * 16 + lg * 4 + r;
                if (row < n) pb[(size_t)row * DOUT + col] = (unsigned short)f2bf(acc2[t][r]);
            }
        }
    }
}

// -- layer 2 gather (bf16 p): 2 nodes/wave, uint4 esrc batch (8 edges), unroll-8 --
__global__ void k_gather2_lsm(const unsigned* __restrict__ pbu,
                              const unsigned short* __restrict__ esrc,
                              const int* __restrict__ row_ptr, const int* __restrict__ row_end,
                              const float* __restrict__ dinv, const float* __restrict__ b2,
                              float* __restrict__ out, int n) {
    int wid = (blockIdx.x * blockDim.x + threadIdx.x) >> 6;
    int lane = threadIdx.x & 63;
    int node = wid * 2 + (lane >> 5);
    int hl = lane & 31;
    if (node >= n) return;
    int beg = row_ptr[node], end = row_end[node];
    float dn = dinv[node];
    int cl = (hl < 20) ? hl : 0;   // clamped uint column (2 bf16 cols per uint)
    unsigned pv = pbu[(size_t)node * 20 + cl];
    float accx = dn * bflo(pv);
    float accy = dn * bfhi(pv);
    int t = beg;
    for (; t + 8 <= end; t += 8) {
        uint4 q = *(const uint4*)(esrc + t);
        int s0 = q.x & 0xffff, s1 = q.x >> 16, s2 = q.y & 0xffff, s3 = q.y >> 16;
        int s4 = q.z & 0xffff, s5 = q.z >> 16, s6 = q.w & 0xffff, s7 = q.w >> 16;
        float w0 = dinv[s0], w1 = dinv[s1], w2 = dinv[s2], w3 = dinv[s3];
        float w4 = dinv[s4], w5 = dinv[s5], w6 = dinv[s6], w7 = dinv[s7];
        unsigned p0 = pbu[(size_t)s0 * 20 + cl], p1 = pbu[(size_t)s1 * 20 + cl];
        unsigned p2 = pbu[(size_t)s2 * 20 + cl], p3 = pbu[(size_t)s3 * 20 + cl];
        unsigned p4 = pbu[(size_t)s4 * 20 + cl], p5 = pbu[(size_t)s5 * 20 + cl];
        unsigned p6 = pbu[(size_t)s6 * 20 + cl], p7 = pbu[(size_t)s7 * 20 + cl];
        accx += w0 * bflo(p0) + w1 * bflo(p1) + w2 * bflo(p2) + w3 * bflo(p3)
              + w4 * bflo(p4) + w5 * bflo(p5) + w6 * bflo(p6) + w7 * bflo(p7);
        accy += w0 * bfhi(p0) + w1 * bfhi(p1) + w2 * bfhi(p2) + w3 * bfhi(p3)
              + w4 * bfhi(p4) + w5 * bfhi(p5) + w6 * bfhi(p6) + w7 * bfhi(p7);
    }
    for (; t < end; ++t) {
        int s = esrc[t];
        float w = dinv[s];
        unsigned p = pbu[(size_t)s * 20 + cl];
        accx += w * bflo(p);
        accy += w * bfhi(p);
    }
    float vx = -INFINITY, vy = -INFINITY;
    if (hl < 20) {
        float2 bv = ((const float2*)b2)[hl];
        vx = dn * accx + bv.x;
        vy = dn * accy + bv.y;
    }
    float m = fmaxf(vx, vy);
#pragma unroll
    for (int off = 16; off; off >>= 1) m = fmaxf(m, __shfl_xor(m, off, 32));
    float ex = (hl < 20) ? (expf(vx - m) + expf(vy - m)) : 0.f;
    float ssum = ex;
#pragma unroll
    for (int off = 16; off; off >>= 1) ssum += __shfl_xor(ssum, off, 32);
    float ls = logf(ssum);
    if (hl < 20)
        ((float2*)(out + (size_t)node * DOUT))[hl] = make_float2(vx - m - ls, vy - m - ls);
}

extern "C" void kernel_launch(void* const* d_in, const int* in_sizes, int n_in,
                              void* d_out, int out_size, void* d_ws, size_t ws_size,
                              hipStream_t stream) {
    const float* x  = (const float*)d_in[0];
    const int*   ei = (const int*)d_in[1];
    const float* W1 = (const float*)d_in[2];
    const float* b1 = (const float*)d_in[3];
    const float* W2 = (const float*)d_in[4];
    const float* b2 = (const float*)d_in[5];
    float* out = (float*)d_out;

    int n = in_sizes[0] / DIN;   // 50000
    int E = in_sizes[1] / 2;     // 800000
    const int* src = ei;
    const int* dst = ei + E;

    // workspace layout (~36 MB)
    int*            gcur    = (int*)d_ws;                          // 512 (NBUK used)
    int*            row_ptr = gcur + 512;                          // n
    int*            row_end = row_ptr + n;                         // n
    float*          dinv    = (float*)(row_end + n);               // n
    unsigned*       w1t     = (unsigned*)(dinv + n);               // 16384
    unsigned*       w2t     = w1t + 16384;                         // 6144
    unsigned*       raw     = w2t + 6144;                          // NBUK*CAP uint
    unsigned short* esrc    = (unsigned short*)(raw + (size_t)NBUK * CAP); // NBUK*CAP us
    unsigned*       xb      = (unsigned*)(esrc + (size_t)NBUK * CAP);      // n*64
    unsigned*       axb     = xb + (size_t)n * 64;                 // n*64
    unsigned short* pb      = (unsigned short*)xb;                 // n*40 bf16, overlays dead xb

    const int B = 256;
    int part_blocks = (E + PART_CHUNK - 1) / PART_CHUNK;           // 196
    int prep_items = n * 64 + 256 * 64 + 48 * 128 + NBUK;
    int npairs = (n + 1) / 2;                                      // 2 nodes per wave
    int gath_blocks = (int)(((size_t)npairs * 64 + B - 1) / B);

    k_prep<<<(prep_items + B - 1) / B, B, 0, stream>>>(x, W1, W2, xb, w1t, w2t, gcur, n * 64);
    k_partition<<<part_blocks, PART_T, 0, stream>>>(src, dst, gcur, raw, E);
    k_bucket_csr<<<NBUK, B, 0, stream>>>(raw, gcur, row_ptr, row_end, dinv, esrc, n);
    k_gather_agg1<<<gath_blocks, B, 0, stream>>>(
        (const uint2*)xb, esrc, row_ptr, row_end, dinv, (uint2*)axb, n);
    k_mlp_mfma<<<(n + MLP_ROWS - 1) / MLP_ROWS, B, 0, stream>>>(
        (const unsigned short*)axb, (const unsigned short*)w1t, b1,
        (const unsigned short*)w2t, pb, n);
    k_gather2_lsm<<<gath_blocks, B, 0, stream>>>(
        (const unsigned*)pb, esrc, row_ptr, row_end, dinv, b2, out, n);
}